// Round 6
// baseline (144.879 us; speedup 1.0000x reference)
//
#include <hip/hip_runtime.h>

// Problem constants (match reference)
constexpr int B        = 65536;
constexpr int N_SPARSE = 20;
constexpr int N_VARLEN = 3;
constexpr int SEQ_LEN  = 50;
constexpr int VOCAB    = 100000;
constexpr int N_DENSE  = 13;
constexpr int VAR_TOT  = N_VARLEN * SEQ_LEN;  // 150

typedef int   v4i __attribute__((ext_vector_type(4)));
typedef float v2f __attribute__((ext_vector_type(2)));
typedef float v4f __attribute__((ext_vector_type(4)));

// 16 lanes handle FOUR rows (two row-pairs 2u, 2u+1), software-pipelined:
// both pairs' id loads issue first, then both pairs' gathers — the second
// pair's id-load latency hides under the first pair's gather latency,
// doubling each wave's outstanding-gather duty cycle (the R4 post-mortem
// model: per-wave serial chain id-wait -> gather-wait is the limiter).
// nt only on streams (ids, dense_x, out); gathers are cached (R3 lesson).
__global__ __launch_bounds__(256) void logit_kernel(
    const int*   __restrict__ sparse_ids,    // [B, 20]
    const int*   __restrict__ varlen_ids,    // [B, 3, 50]
    const float* __restrict__ dense_x,       // [B, 13]
    const float* __restrict__ sparse_tables, // [20, VOCAB]
    const float* __restrict__ varlen_tables, // [3, VOCAB]
    const float* __restrict__ dense_w,       // [13]
    float*       __restrict__ out)           // [B]
{
    const int tid = blockIdx.x * blockDim.x + threadIdx.x;
    const int u   = tid >> 4;     // group index, 0 .. B/4-1 (rows 4u .. 4u+3)
    const int t   = tid & 15;     // lane within group

    // ---- stage 1: issue ALL id / dense stream loads for BOTH pairs (nt) ----
    v4i vid[2][5];
    v4i sid[2];
    v2f dx[2];
    #pragma unroll
    for (int p = 0; p < 2; ++p) {
        const long g = 2L * u + p;                     // row-pair index
        const v4i* vptr = (const v4i*)varlen_ids + g * 75;
        #pragma unroll
        for (int k = 0; k < 4; ++k)
            vid[p][k] = __builtin_nontemporal_load(vptr + (t + 16 * k));
        vid[p][4] = __builtin_nontemporal_load(vptr + (t > 10 ? 74 : t + 64));
        sid[p] = __builtin_nontemporal_load((const v4i*)sparse_ids + g * 10 + (t > 9 ? 9 : t));
        dx[p]  = __builtin_nontemporal_load((const v2f*)dense_x    + g * 13 + (t > 12 ? 12 : t));
    }

    // ---- stage 2: issue ALL table gathers for BOTH pairs (cached) ----
    float vval[2][20];
    float sval[2][4];
    #pragma unroll
    for (int p = 0; p < 2; ++p) {
        #pragma unroll
        for (int k = 0; k < 5; ++k) {
            const int c = (k == 4) ? (t + 64) : (t + 16 * k);   // chunk (>=75 masked later)
            #pragma unroll
            for (int j = 0; j < 4; ++j) {
                const int s = 4 * c + j;
                int pp = (s >= VAR_TOT) ? (s - VAR_TOT) : s;
                pp = (pp > VAR_TOT - 1) ? (VAR_TOT - 1) : pp;   // safe for masked lanes
                const int v = (pp >= 100) ? 2 : (pp >= 50 ? 1 : 0);
                vval[p][4 * k + j] = varlen_tables[v * VOCAB + vid[p][k][j]];
            }
        }
        const int c = (t > 9) ? 9 : t;
        #pragma unroll
        for (int j = 0; j < 4; ++j) {
            const int s = 4 * c + j;
            const int f = (s >= N_SPARSE) ? (s - N_SPARSE) : s;
            sval[p][j] = sparse_tables[f * VOCAB + sid[p][j]];
        }
    }

    // ---- stage 3: masked accumulation ----
    float acc[2][2] = {{0.f, 0.f}, {0.f, 0.f}};   // [pair][row-in-pair]
    #pragma unroll
    for (int p = 0; p < 2; ++p) {
        #pragma unroll
        for (int k = 0; k < 5; ++k) {
            const int c = (k == 4) ? (t + 64) : (t + 16 * k);
            #pragma unroll
            for (int j = 0; j < 4; ++j) {
                const int s   = 4 * c + j;
                const bool ok = (s < 2 * VAR_TOT);
                const bool r1 = (s >= VAR_TOT);
                const float m = (ok && vid[p][k][j] != 0) ? vval[p][4 * k + j] : 0.f;
                acc[p][0] += r1 ? 0.f : m;
                acc[p][1] += r1 ? m   : 0.f;
            }
        }
        {
            const int c   = (t > 9) ? 9 : t;
            const bool ok = (t < 10);
            #pragma unroll
            for (int j = 0; j < 4; ++j) {
                const int s   = 4 * c + j;
                const bool r1 = (s >= N_SPARSE);
                const float m = ok ? sval[p][j] : 0.f;
                acc[p][0] += r1 ? 0.f : m;
                acc[p][1] += r1 ? m   : 0.f;
            }
        }
        {
            const int c   = (t > 12) ? 12 : t;
            const bool ok = (t < 13);
            #pragma unroll
            for (int j = 0; j < 2; ++j) {
                const int s   = 2 * c + j;
                const bool r1 = (s >= N_DENSE);
                const int d   = r1 ? (s - N_DENSE) : s;
                const float m = ok ? dx[p][j] * dense_w[d] : 0.f;
                acc[p][0] += r1 ? 0.f : m;
                acc[p][1] += r1 ? m   : 0.f;
            }
        }
    }

    // ---- reduce across the 16-lane group; one float4 store per 4 rows ----
    #pragma unroll
    for (int o = 1; o < 16; o <<= 1) {
        #pragma unroll
        for (int p = 0; p < 2; ++p) {
            acc[p][0] += __shfl_xor(acc[p][0], o);
            acc[p][1] += __shfl_xor(acc[p][1], o);
        }
    }
    if (t == 0) {
        v4f r = { acc[0][0], acc[0][1], acc[1][0], acc[1][1] };
        __builtin_nontemporal_store(r, (v4f*)out + u);
    }
}

extern "C" void kernel_launch(void* const* d_in, const int* in_sizes, int n_in,
                              void* d_out, int out_size, void* d_ws, size_t ws_size,
                              hipStream_t stream) {
    const int*   sparse_ids    = (const int*)d_in[0];
    const int*   varlen_ids    = (const int*)d_in[1];
    const float* dense_x       = (const float*)d_in[2];
    const float* sparse_tables = (const float*)d_in[3];
    const float* varlen_tables = (const float*)d_in[4];
    const float* dense_w       = (const float*)d_in[5];
    float*       out           = (float*)d_out;

    const int threads = 256;
    const int total   = (B / 4) * 16;          // 16 lanes per 4 rows
    const int blocks  = total / threads;       // 1024
    logit_kernel<<<blocks, threads, 0, stream>>>(
        sparse_ids, varlen_ids, dense_x, sparse_tables, varlen_tables, dense_w, out);
}

// Round 7
// 144.064 us; speedup vs baseline: 1.0057x; 1.0057x over previous
//
#include <hip/hip_runtime.h>

// Problem constants (match reference)
constexpr int B        = 65536;
constexpr int N_SPARSE = 20;
constexpr int N_VARLEN = 3;
constexpr int SEQ_LEN  = 50;
constexpr int VOCAB    = 100000;
constexpr int N_DENSE  = 13;
constexpr int VAR_TOT  = N_VARLEN * SEQ_LEN;  // 150

typedef int   v4i __attribute__((ext_vector_type(4)));
typedef float v2f __attribute__((ext_vector_type(2)));

// CK-style raw buffer load bound to the LLVM intrinsic. aux (cachepolicy):
// bit0 = sc0. On gfx940+ sc0=1 on a load = device-coherent => BYPASS the
// non-coherent per-CU L1, service directly from L2.
// R5 post-mortem: gather rate is pinned at ~0.31 lanes/cyc/CU regardless of
// waves x per-wave-ILP => per-CU L1 miss-queue is the suspected cap. Random
// gathers have ~0% L1 hit rate anyway; skip L1 entirely.
__device__ float llvm_amdgcn_raw_buffer_load_fp32(v4i srsrc, int voffset,
                                                  int soffset, int cachepolicy)
    __asm("llvm.amdgcn.raw.buffer.load.f32");

__device__ inline v4i make_srd(const void* p, unsigned bytes) {
    const unsigned long long a = (unsigned long long)p;
    v4i r;
    r.x = (int)(unsigned)a;          // base[31:0]
    r.y = (int)(unsigned)(a >> 32);  // base[47:32], stride=0
    r.z = (int)bytes;                // num_records (bytes when stride==0)
    r.w = 0x00020000;                // raw dword access
    return r;
}

// 16 lanes per row PAIR (rows 2g, 2g+1); every stream load naturally aligned:
// varlen pair = 75 x int4, sparse pair = 10 x int4, dense pair = 13 x float2.
// nt on streams only (ids, dense_x, out); table gathers via sc0 buffer loads
// (L1-bypass, L2-cached). 32-bit voffset addressing removes 64-bit addr math.
__global__ __launch_bounds__(256) void logit_kernel(
    const int*   __restrict__ sparse_ids,    // [B, 20]
    const int*   __restrict__ varlen_ids,    // [B, 3, 50]
    const float* __restrict__ dense_x,       // [B, 13]
    const float* __restrict__ sparse_tables, // [20, VOCAB]
    const float* __restrict__ varlen_tables, // [3, VOCAB]
    const float* __restrict__ dense_w,       // [13]
    float*       __restrict__ out)           // [B]
{
    const int tid = blockIdx.x * blockDim.x + threadIdx.x;
    const int g   = tid >> 4;     // row-pair index, 0 .. B/2-1
    const int t   = tid & 15;     // lane within pair-group

    const v4i vsrd = make_srd(varlen_tables, N_VARLEN * VOCAB * 4);
    const v4i ssrd = make_srd(sparse_tables, N_SPARSE * VOCAB * 4);

    const v4i* vptr = (const v4i*)varlen_ids + (long)g * 75;
    const v4i* sptr = (const v4i*)sparse_ids + (long)g * 10;
    const v2f* dptr = (const v2f*)dense_x    + (long)g * 13;

    // ---- stage 1: issue ALL id / dense stream loads (non-temporal) ----
    v4i vid[5];
    #pragma unroll
    for (int k = 0; k < 4; ++k)
        vid[k] = __builtin_nontemporal_load(vptr + (t + 16 * k));       // chunks 0..63
    vid[4] = __builtin_nontemporal_load(vptr + (t > 10 ? 74 : t + 64)); // 64..74 (clamped)
    const v4i sid = __builtin_nontemporal_load(sptr + (t > 9 ? 9 : t));   // clamped
    const v2f dx  = __builtin_nontemporal_load(dptr + (t > 12 ? 12 : t)); // clamped

    float acc0 = 0.f, acc1 = 0.f;   // rows 2g, 2g+1

    // ---- varlen gathers: chunk c covers pair-positions s = 4c .. 4c+3 ----
    #pragma unroll
    for (int k = 0; k < 5; ++k) {
        const int c = (k == 4) ? (t + 64) : (t + 16 * k);  // >=75 => masked below
        #pragma unroll
        for (int j = 0; j < 4; ++j) {
            const int s   = 4 * c + j;                     // pair-position (0..319)
            const bool ok = (s < 2 * VAR_TOT);
            const bool r1 = (s >= VAR_TOT);
            int p = r1 ? (s - VAR_TOT) : s;
            p = (p > VAR_TOT - 1) ? (VAR_TOT - 1) : p;     // safe for masked lanes
            const int v  = (p >= 100) ? 2 : (p >= 50 ? 1 : 0);
            const int id = vid[k][j];
            const float val =
                llvm_amdgcn_raw_buffer_load_fp32(vsrd, 4 * (v * VOCAB + id), 0, 1);
            const float m = (ok && id != 0) ? val : 0.f;
            acc0 += r1 ? 0.f : m;
            acc1 += r1 ? m   : 0.f;
        }
    }

    // ---- sparse gathers: chunk t covers s = 4t .. 4t+3 (valid t < 10) ----
    {
        const int c   = (t > 9) ? 9 : t;
        const bool ok = (t < 10);
        #pragma unroll
        for (int j = 0; j < 4; ++j) {
            const int s   = 4 * c + j;
            const bool r1 = (s >= N_SPARSE);
            const int f   = r1 ? (s - N_SPARSE) : s;
            const float val =
                llvm_amdgcn_raw_buffer_load_fp32(ssrd, 4 * (f * VOCAB + sid[j]), 0, 1);
            const float m = ok ? val : 0.f;
            acc0 += r1 ? 0.f : m;
            acc1 += r1 ? m   : 0.f;
        }
    }

    // ---- dense: chunk t covers s = 2t, 2t+1 (valid t < 13) ----
    {
        const int c   = (t > 12) ? 12 : t;
        const bool ok = (t < 13);
        #pragma unroll
        for (int j = 0; j < 2; ++j) {
            const int s   = 2 * c + j;
            const bool r1 = (s >= N_DENSE);
            const int d   = r1 ? (s - N_DENSE) : s;
            const float m = ok ? dx[j] * dense_w[d] : 0.f;
            acc0 += r1 ? 0.f : m;
            acc1 += r1 ? m   : 0.f;
        }
    }

    // ---- reduce across the 16-lane group, one float2 store per pair ----
    #pragma unroll
    for (int o = 1; o < 16; o <<= 1) {
        acc0 += __shfl_xor(acc0, o);
        acc1 += __shfl_xor(acc1, o);
    }
    if (t == 0) {
        v2f r = { acc0, acc1 };
        __builtin_nontemporal_store(r, (v2f*)out + g);
    }
}

extern "C" void kernel_launch(void* const* d_in, const int* in_sizes, int n_in,
                              void* d_out, int out_size, void* d_ws, size_t ws_size,
                              hipStream_t stream) {
    const int*   sparse_ids    = (const int*)d_in[0];
    const int*   varlen_ids    = (const int*)d_in[1];
    const float* dense_x       = (const float*)d_in[2];
    const float* sparse_tables = (const float*)d_in[3];
    const float* varlen_tables = (const float*)d_in[4];
    const float* dense_w       = (const float*)d_in[5];
    float*       out           = (float*)d_out;

    const int threads = 256;
    const int total   = (B / 2) * 16;          // 16 lanes per row-pair
    const int blocks  = total / threads;       // 2048
    logit_kernel<<<blocks, threads, 0, stream>>>(
        sparse_ids, varlen_ids, dense_x, sparse_tables, varlen_tables, dense_w, out);
}